// Round 1
// baseline (3072.880 us; speedup 1.0000x reference)
//
#include <hip/hip_runtime.h>
#include <math.h>

#define N_PTS 4096
#define BATCH 4
#define KNB 20

__device__ __forceinline__ float lrelu(float v){ return fmaxf(v, 0.2f*v); }
__device__ __forceinline__ unsigned fenc(float f){ unsigned u=__float_as_uint(f); return (u&0x80000000u)?~u:(u|0x80000000u); }
__device__ __forceinline__ float fdec(unsigned k){ return (k&0x80000000u)?__uint_as_float(k&0x7fffffffu):__uint_as_float(~k); }

// ---- prep: fold BN scale into weights ----
__global__ void k_scale_rows(const float* __restrict__ W, const float* __restrict__ bn,
                             float* __restrict__ Wf, float* __restrict__ bias, int O, int C){
  int i = blockIdx.x*256 + threadIdx.x;
  if (i >= O*C) return;
  int o = i / C;
  float s = bn[o] / sqrtf(bn[3*O+o] + 1e-5f);
  Wf[i] = W[i]*s;
  if (i % C == 0) bias[o] = bn[O+o] - s*bn[2*O+o];
}

// transposed float4-chunk layout: dst[(c/4)*256 + o*4 + c%4], O=64 fixed
__global__ void k_build_T4(const float* __restrict__ W, int ldw, const float* __restrict__ bn,
                           float* __restrict__ dst, float* __restrict__ bias,
                           int c0, int diffoff, int Csrc){
  int o = threadIdx.x, c = blockIdx.x;
  float s = bn[o] / sqrtf(bn[192+o] + 1e-5f);
  float val = 0.f;
  if (c < Csrc){
    val = W[o*ldw + c0 + c];
    if (diffoff) val = W[o*ldw + c0 + diffoff + c] - val;
    val *= s;
  }
  dst[(c>>2)*256 + o*4 + (c&3)] = val;
  if (bias != nullptr && c==0) bias[o] = bn[64+o] - s*bn[128+o];
}

// U1[b][k][o] = sum_{c<6} s_o*W1[o][c]*x[b][c][k]  (first-KNN neighbors are points 0..19)
__global__ void k_build_U1(const float* __restrict__ x, const float* __restrict__ W1,
                           const float* __restrict__ bn, float* __restrict__ U1){
  int o = threadIdx.x, k = blockIdx.x, b = blockIdx.y;
  float s = bn[o] / sqrtf(bn[192+o] + 1e-5f);
  float acc = 0.f;
  #pragma unroll
  for (int c=0;c<6;c++) acc += W1[o*12+c] * x[(b*6+c)*N_PTS + k];
  U1[(b*KNB+k)*64 + o] = acc*s;
}

__global__ void k_init_g(unsigned* g){ g[blockIdx.x*256+threadIdx.x] = fenc(-INFINITY); }

// ---- edge block 1 (trivial neighbors 0..19) : conv1 + conv2 + maxpool ----
__global__ __launch_bounds__(256) void k_edge1(const float* __restrict__ x, const float* __restrict__ U1,
                        const float* __restrict__ W1dT4, const float* __restrict__ bf1,
                        const float* __restrict__ W2T4, const float* __restrict__ bf2,
                        float* __restrict__ x1t, float* __restrict__ Xcat, float* __restrict__ xx1){
  __shared__ float hb[4][KNB][64];
  int wid = threadIdx.x>>6, lane = threadIdx.x&63;
  int pt = blockIdx.x*4 + wid, b = pt>>12, n = pt&4095;
  float xv[8];
  #pragma unroll
  for (int c=0;c<6;c++) xv[c] = x[(b*6+c)*N_PTS + n];
  xv[6]=0.f; xv[7]=0.f;
  float w = bf1[lane];
  #pragma unroll
  for (int cb=0;cb<2;cb++){
    float4 wv = ((const float4*)W1dT4)[cb*64+lane];
    w = fmaf(wv.x, xv[cb*4+0], w); w = fmaf(wv.y, xv[cb*4+1], w);
    w = fmaf(wv.z, xv[cb*4+2], w); w = fmaf(wv.w, xv[cb*4+3], w);
  }
  const float* Ub = U1 + b*KNB*64;
  #pragma unroll
  for (int k=0;k<KNB;k++) hb[wid][k][lane] = lrelu(Ub[k*64+lane] + w);
  __syncthreads();
  float acc[KNB];
  #pragma unroll
  for (int k=0;k<KNB;k++) acc[k] = bf2[lane];
  for (int cb=0;cb<16;cb++){
    float4 wv = ((const float4*)W2T4)[cb*64+lane];
    #pragma unroll
    for (int k=0;k<KNB;k++){
      float4 a = *(const float4*)&hb[wid][k][cb*4];
      acc[k]=fmaf(wv.x,a.x,acc[k]); acc[k]=fmaf(wv.y,a.y,acc[k]);
      acc[k]=fmaf(wv.z,a.z,acc[k]); acc[k]=fmaf(wv.w,a.w,acc[k]);
    }
  }
  float mx = -INFINITY;
  #pragma unroll
  for (int k=0;k<KNB;k++) mx = fmaxf(mx, lrelu(acc[k]));
  x1t[(size_t)pt*64 + lane] = mx;
  Xcat[((size_t)b*192 + 0 + lane)*N_PTS + n] = mx;
  float sq = mx*mx;
  #pragma unroll
  for (int off=32; off; off>>=1) sq += __shfl_xor(sq, off);
  if (lane==0) xx1[pt] = sq;
}

// ---- KNN pairwise kernel: pd[b][i][j] = fma(2,dot,-xx_n) - xx_m, 128x128 tile, K=64 ----
__global__ __launch_bounds__(256) void k_knn_gemm(const float* __restrict__ xt, const float* __restrict__ xx,
                          float* __restrict__ pd, int q0){
  __shared__ float As[64][132];
  __shared__ float Bs[64][132];
  int tid = threadIdx.x;
  int bx = blockIdx.x, by = blockIdx.y, b = blockIdx.z;
  const float* xb = xt + (size_t)b*N_PTS*64;
  #pragma unroll
  for (int p=0;p<8;p++){
    int row = (tid>>4) + p*16, c4 = tid&15;
    float4 av = *(const float4*)&xb[(size_t)(q0 + by*128 + row)*64 + c4*4];
    As[c4*4+0][row]=av.x; As[c4*4+1][row]=av.y; As[c4*4+2][row]=av.z; As[c4*4+3][row]=av.w;
    float4 bv = *(const float4*)&xb[(size_t)(bx*128 + row)*64 + c4*4];
    Bs[c4*4+0][row]=bv.x; Bs[c4*4+1][row]=bv.y; Bs[c4*4+2][row]=bv.z; Bs[c4*4+3][row]=bv.w;
  }
  __syncthreads();
  int u = tid&15, v = tid>>4;
  float acc[8][8];
  #pragma unroll
  for (int i=0;i<8;i++)
    #pragma unroll
    for (int j=0;j<8;j++) acc[i][j]=0.f;
  #pragma unroll 4
  for (int k=0;k<64;k++){
    float4 a0 = *(const float4*)&As[k][u*4];
    float4 a1 = *(const float4*)&As[k][64+u*4];
    float4 b0 = *(const float4*)&Bs[k][v*4];
    float4 b1 = *(const float4*)&Bs[k][64+v*4];
    float a[8] = {a0.x,a0.y,a0.z,a0.w,a1.x,a1.y,a1.z,a1.w};
    float bb[8] = {b0.x,b0.y,b0.z,b0.w,b1.x,b1.y,b1.z,b1.w};
    #pragma unroll
    for (int i=0;i<8;i++)
      #pragma unroll
      for (int j=0;j<8;j++)
        acc[i][j] = fmaf(a[i], bb[j], acc[i][j]);
  }
  float xn[8], xm[8];
  #pragma unroll
  for (int i=0;i<8;i++){
    int ri = (i<4)? u*4+i : 64+u*4+(i-4);
    xn[i] = xx[b*N_PTS + q0 + by*128 + ri];
  }
  #pragma unroll
  for (int j=0;j<8;j++){
    int cj = (j<4)? v*4+j : 64+v*4+(j-4);
    xm[j] = xx[b*N_PTS + bx*128 + cj];
  }
  #pragma unroll
  for (int i=0;i<8;i++){
    int ri = (i<4)? u*4+i : 64+u*4+(i-4);
    float* dst = pd + ((size_t)(b*512 + by*128 + ri))*N_PTS + bx*128;
    float4 s0, s1;
    s0.x = fmaf(2.f,acc[i][0],-xn[i]) - xm[0];
    s0.y = fmaf(2.f,acc[i][1],-xn[i]) - xm[1];
    s0.z = fmaf(2.f,acc[i][2],-xn[i]) - xm[2];
    s0.w = fmaf(2.f,acc[i][3],-xn[i]) - xm[3];
    s1.x = fmaf(2.f,acc[i][4],-xn[i]) - xm[4];
    s1.y = fmaf(2.f,acc[i][5],-xn[i]) - xm[5];
    s1.z = fmaf(2.f,acc[i][6],-xn[i]) - xm[6];
    s1.w = fmaf(2.f,acc[i][7],-xn[i]) - xm[7];
    *(float4*)&dst[v*4] = s0;
    *(float4*)&dst[64+v*4] = s1;
  }
}

// ---- top-20 with exact lax.top_k tie-break (val desc, index asc); one wave per query ----
__global__ __launch_bounds__(256) void k_topk20(const float* __restrict__ pdbuf, int* __restrict__ idx, int q0){
  int wid = threadIdx.x>>6, lane = threadIdx.x&63;
  int gw = blockIdx.x*4 + wid;
  int b = gw >> 9, i = gw & 511;
  const float* row = pdbuf + ((size_t)b*512 + i)*N_PTS;
  float v[64];
  #pragma unroll
  for (int t=0;t<64;t++) v[t] = row[t*64+lane];
  float wv = INFINITY; int wm = -1;
  int myidx = 0;
  for (int r=0;r<KNB;r++){
    float bv = -INFINITY; int bm = 0x7fffffff;
    #pragma unroll
    for (int t=0;t<64;t++){
      int m = t*64+lane;
      bool sel = (v[t] > wv) || (v[t]==wv && m <= wm);     // already taken
      bool better = (!sel) && ((v[t] > bv) || (v[t]==bv && m < bm));
      if (better){ bv=v[t]; bm=m; }
    }
    #pragma unroll
    for (int off=32; off; off>>=1){
      float ov = __shfl_xor(bv, off); int om = __shfl_xor(bm, off);
      if (ov > bv || (ov==bv && om < bm)) { bv=ov; bm=om; }
    }
    wv=bv; wm=bm;
    if (lane==r) myidx = wm;
  }
  if (lane < KNB) idx[((size_t)b*N_PTS + (q0+i))*KNB + lane] = myidx;
}

// ---- edge conv block (gather + 1 or 2 convs + maxpool) ----
template<int TWO>
__global__ __launch_bounds__(256) void k_edgeconv(const float* __restrict__ xt, const int* __restrict__ idx,
    const float* __restrict__ WLT4, const float* __restrict__ WRT4, const float* __restrict__ bfa,
    const float* __restrict__ W2T4, const float* __restrict__ bfb,
    float* __restrict__ xout, float* __restrict__ Xcat, int rowofs, float* __restrict__ xxout){
  __shared__ float A[4][KNB][64];
  __shared__ float H[4][TWO?KNB:1][64];
  __shared__ float Cs[4][64];
  int wid = threadIdx.x>>6, lane = threadIdx.x&63;
  int pt = blockIdx.x*4 + wid, b = pt>>12, n = pt&4095;
  const float* xb = xt + (size_t)b*N_PTS*64;
  float ctr = xb[(size_t)n*64 + lane];
  Cs[wid][lane] = ctr;
  const int* ip = idx + (size_t)pt*KNB;
  #pragma unroll
  for (int k=0;k<KNB;k++){
    int m = ip[k];
    A[wid][k][lane] = xb[(size_t)m*64 + lane] - ctr;
  }
  __syncthreads();
  float e = bfa[lane];
  #pragma unroll
  for (int cb=0;cb<16;cb++){
    float4 wv = ((const float4*)WRT4)[cb*64+lane];
    float4 cv = *(const float4*)&Cs[wid][cb*4];
    e=fmaf(wv.x,cv.x,e); e=fmaf(wv.y,cv.y,e); e=fmaf(wv.z,cv.z,e); e=fmaf(wv.w,cv.w,e);
  }
  float acc[KNB];
  #pragma unroll
  for (int k=0;k<KNB;k++) acc[k]=e;
  for (int cb=0;cb<16;cb++){
    float4 wv = ((const float4*)WLT4)[cb*64+lane];
    #pragma unroll
    for (int k=0;k<KNB;k++){
      float4 a = *(const float4*)&A[wid][k][cb*4];
      acc[k]=fmaf(wv.x,a.x,acc[k]); acc[k]=fmaf(wv.y,a.y,acc[k]);
      acc[k]=fmaf(wv.z,a.z,acc[k]); acc[k]=fmaf(wv.w,a.w,acc[k]);
    }
  }
  if (TWO){
    #pragma unroll
    for (int k=0;k<KNB;k++) H[wid][k][lane] = lrelu(acc[k]);
    __syncthreads();
    #pragma unroll
    for (int k=0;k<KNB;k++) acc[k] = bfb[lane];
    for (int cb=0;cb<16;cb++){
      float4 wv = ((const float4*)W2T4)[cb*64+lane];
      #pragma unroll
      for (int k=0;k<KNB;k++){
        float4 a = *(const float4*)&H[wid][k][cb*4];
        acc[k]=fmaf(wv.x,a.x,acc[k]); acc[k]=fmaf(wv.y,a.y,acc[k]);
        acc[k]=fmaf(wv.z,a.z,acc[k]); acc[k]=fmaf(wv.w,a.w,acc[k]);
      }
    }
  }
  float mx = -INFINITY;
  #pragma unroll
  for (int k=0;k<KNB;k++) mx = fmaxf(mx, lrelu(acc[k]));
  if (xout) xout[(size_t)pt*64 + lane] = mx;
  Xcat[((size_t)b*192 + rowofs + lane)*N_PTS + n] = mx;
  if (xxout){
    float sq = mx*mx;
    #pragma unroll
    for (int off=32;off;off>>=1) sq += __shfl_xor(sq,off);
    if (lane==0) xxout[pt] = sq;
  }
}

// ---- generic fp32 GEMM: C[b][o][n] = act(A(OxK) @ B[b](KxN) + bias), optional col-max atomic ----
// flags: 1=leakyrelu, 2=store C, 4=bias per batch
__global__ __launch_bounds__(256) void k_gemm(const float* __restrict__ A, int lda,
        const float* __restrict__ B, const float* __restrict__ bias,
        float* __restrict__ C, unsigned* __restrict__ gmax,
        int O, int K, int flags){
  __shared__ float As[64][132];
  __shared__ float Bs[64][132];
  int tid = threadIdx.x, bx = blockIdx.x, by = blockIdx.y, b = blockIdx.z;
  int u = tid&15, v = tid>>4;
  float acc[8][8];
  #pragma unroll
  for (int i=0;i<8;i++)
    #pragma unroll
    for (int j=0;j<8;j++) acc[i][j]=0.f;
  const float* Bb = B + (size_t)b*K*N_PTS;
  for (int kt=0; kt<K; kt+=64){
    #pragma unroll
    for (int p=0;p<8;p++){
      int row = (tid>>4) + p*16, c4 = tid&15;
      int ga = by*128 + row;
      float4 av = (ga < O) ? *(const float4*)&A[(size_t)ga*lda + kt + c4*4] : make_float4(0.f,0.f,0.f,0.f);
      As[c4*4+0][row]=av.x; As[c4*4+1][row]=av.y; As[c4*4+2][row]=av.z; As[c4*4+3][row]=av.w;
      int kk = p*8 + (tid>>5), n4 = tid&31;
      float4 bv = *(const float4*)&Bb[(size_t)(kt+kk)*N_PTS + bx*128 + n4*4];
      *(float4*)&Bs[kk][n4*4] = bv;
    }
    __syncthreads();
    #pragma unroll 4
    for (int k=0;k<64;k++){
      float4 a0 = *(const float4*)&As[k][u*4];
      float4 a1 = *(const float4*)&As[k][64+u*4];
      float4 b0 = *(const float4*)&Bs[k][v*4];
      float4 b1 = *(const float4*)&Bs[k][64+v*4];
      float a[8] = {a0.x,a0.y,a0.z,a0.w,a1.x,a1.y,a1.z,a1.w};
      float bb[8] = {b0.x,b0.y,b0.z,b0.w,b1.x,b1.y,b1.z,b1.w};
      #pragma unroll
      for (int i=0;i<8;i++)
        #pragma unroll
        for (int j=0;j<8;j++)
          acc[i][j] = fmaf(a[i], bb[j], acc[i][j]);
    }
    __syncthreads();
  }
  bool relu = flags&1, store = flags&2, pbb = flags&4;
  float rowm[8];
  #pragma unroll
  for (int i=0;i<8;i++){
    int rl = (i<4)? u*4+i : 64+u*4+(i-4);
    int ri = by*128 + rl;
    float bvv = (bias != nullptr && ri < O) ? (pbb ? bias[b*O+ri] : bias[ri]) : 0.f;
    float vals[8];
    #pragma unroll
    for (int j=0;j<8;j++){
      float y = acc[i][j] + bvv;
      if (relu) y = lrelu(y);
      vals[j]=y;
    }
    if (store && ri < O){
      float* dst = C + ((size_t)b*O+ri)*N_PTS + bx*128;
      *(float4*)&dst[v*4] = make_float4(vals[0],vals[1],vals[2],vals[3]);
      *(float4*)&dst[64+v*4] = make_float4(vals[4],vals[5],vals[6],vals[7]);
    }
    float m = vals[0];
    #pragma unroll
    for (int j=1;j<8;j++) m = fmaxf(m, vals[j]);
    rowm[i] = m;
  }
  if (gmax != nullptr){
    float* red = &Bs[0][0];   // reuse as [128][16]
    #pragma unroll
    for (int i=0;i<8;i++){
      int rl = (i<4)? u*4+i : 64+u*4+(i-4);
      red[rl*16 + v] = rowm[i];
    }
    __syncthreads();
    if (tid < 128){
      float m = red[tid*16];
      #pragma unroll
      for (int j=1;j<16;j++) m = fmaxf(m, red[tid*16+j]);
      atomicMax(&gmax[b*1024 + by*128 + tid], fenc(m));
    }
  }
}

// bias7[b][o] = sum_{c<1024} Wf7[o][c]*g[b][c] + bf7[o]
__global__ __launch_bounds__(256) void k_gemv7(const float* __restrict__ Wf7, const float* __restrict__ bf7,
                        const unsigned* __restrict__ g, float* __restrict__ bias7){
  int wid = threadIdx.x>>6, lane = threadIdx.x&63;
  int o = blockIdx.x*4 + wid, b = blockIdx.y;
  const float* wr = Wf7 + (size_t)o*1216;
  const unsigned* gb = g + b*1024;
  float acc = 0.f;
  for (int c = lane; c < 1024; c += 64)
    acc = fmaf(wr[c], fdec(gb[c]), acc);
  #pragma unroll
  for (int off=32; off; off>>=1) acc += __shfl_xor(acc, off);
  if (lane==0) bias7[b*512+o] = acc + bf7[o];
}

extern "C" void kernel_launch(void* const* d_in, const int* in_sizes, int n_in,
                              void* d_out, int out_size, void* d_ws, size_t ws_size,
                              hipStream_t stream){
  const float* x  = (const float*)d_in[0];
  const float* W1 = (const float*)d_in[1];
  const float* W2 = (const float*)d_in[2];
  const float* W3 = (const float*)d_in[3];
  const float* W4 = (const float*)d_in[4];
  const float* W5 = (const float*)d_in[5];
  const float* W6 = (const float*)d_in[6];
  const float* W7 = (const float*)d_in[7];
  const float* W8 = (const float*)d_in[8];
  const float* W9 = (const float*)d_in[9];
  const float* bn1 = (const float*)d_in[10];
  const float* bn2 = (const float*)d_in[11];
  const float* bn3 = (const float*)d_in[12];
  const float* bn4 = (const float*)d_in[13];
  const float* bn5 = (const float*)d_in[14];
  const float* bn6 = (const float*)d_in[15];
  const float* bn7 = (const float*)d_in[16];
  const float* bn8 = (const float*)d_in[17];

  float* ws = (float*)d_ws;
  size_t off = 0;
  auto alloc = [&](size_t nf){ float* p = ws + off; off += (nf + 63) & ~(size_t)63; return p; };
  float* Wf6 = alloc(1024*192);   float* bf6 = alloc(1024);
  float* Wf7 = alloc((size_t)512*1216); float* bf7 = alloc(512);
  float* Wf8 = alloc(256*512);    float* bf8 = alloc(256);
  float* W1dT4 = alloc(8*64);     float* bf1 = alloc(64);
  float* W2T4  = alloc(64*64);    float* bf2 = alloc(64);
  float* W3LT4 = alloc(64*64);    float* W3RT4 = alloc(64*64); float* bf3 = alloc(64);
  float* W4T4  = alloc(64*64);    float* bf4 = alloc(64);
  float* W5LT4 = alloc(64*64);    float* W5RT4 = alloc(64*64); float* bf5 = alloc(64);
  float* U1  = alloc(4*KNB*64);
  float* x1t = alloc((size_t)4*N_PTS*64);
  float* x2t = alloc((size_t)4*N_PTS*64);
  float* Xcat = alloc((size_t)4*192*N_PTS);
  float* xx1 = alloc(4*N_PTS);
  float* xx2 = alloc(4*N_PTS);
  int* idx1 = (int*)alloc((size_t)4*N_PTS*KNB);
  int* idx2 = (int*)alloc((size_t)4*N_PTS*KNB);
  unsigned* genc = (unsigned*)alloc(4*1024);
  float* bias7 = alloc(4*512);
  float* pdbuf = alloc((size_t)4*512*N_PTS);   // 32 MB stripe buffer; reused as h7 afterwards
  float* h7 = pdbuf;
  float* h8 = alloc((size_t)4*256*N_PTS);

  // prep (every call: deterministic)
  k_scale_rows<<<(1024*192+255)/256,256,0,stream>>>(W6, bn6, Wf6, bf6, 1024, 192);
  k_scale_rows<<<(512*1216+255)/256,256,0,stream>>>(W7, bn7, Wf7, bf7, 512, 1216);
  k_scale_rows<<<(256*512+255)/256,256,0,stream>>>(W8, bn8, Wf8, bf8, 256, 512);
  k_build_T4<<<8,64,0,stream>>>(W1, 12, bn1, W1dT4, bf1, 0, 6, 6);     // (W1R - W1L), pad to 8
  k_build_T4<<<64,64,0,stream>>>(W2, 64, bn2, W2T4, bf2, 0, 0, 64);
  k_build_T4<<<64,64,0,stream>>>(W3, 128, bn3, W3LT4, bf3, 0, 0, 64);
  k_build_T4<<<64,64,0,stream>>>(W3, 128, bn3, W3RT4, nullptr, 64, 0, 64);
  k_build_T4<<<64,64,0,stream>>>(W4, 64, bn4, W4T4, bf4, 0, 0, 64);
  k_build_T4<<<64,64,0,stream>>>(W5, 128, bn5, W5LT4, bf5, 0, 0, 64);
  k_build_T4<<<64,64,0,stream>>>(W5, 128, bn5, W5RT4, nullptr, 64, 0, 64);
  k_build_U1<<<dim3(KNB,4),64,0,stream>>>(x, W1, bn1, U1);
  k_init_g<<<16,256,0,stream>>>(genc);

  // edge block 1 (neighbors = points 0..19 since KNN input is empty slice)
  k_edge1<<<4096,256,0,stream>>>(x, U1, W1dT4, bf1, W2T4, bf2, x1t, Xcat, xx1);

  // KNN on x1 (512-query stripes)
  for (int s=0;s<8;s++){
    k_knn_gemm<<<dim3(32,4,4),256,0,stream>>>(x1t, xx1, pdbuf, s*512);
    k_topk20<<<512,256,0,stream>>>(pdbuf, idx1, s*512);
  }

  // edge block 2 (two convs)
  k_edgeconv<1><<<4096,256,0,stream>>>(x1t, idx1, W3LT4, W3RT4, bf3, W4T4, bf4, x2t, Xcat, 64, xx2);

  // KNN on x2
  for (int s=0;s<8;s++){
    k_knn_gemm<<<dim3(32,4,4),256,0,stream>>>(x2t, xx2, pdbuf, s*512);
    k_topk20<<<512,256,0,stream>>>(pdbuf, idx2, s*512);
  }

  // edge block 3 (one conv)
  k_edgeconv<0><<<4096,256,0,stream>>>(x2t, idx2, W5LT4, W5RT4, bf5, nullptr, nullptr, nullptr, Xcat, 128, nullptr);

  // conv6 (1024x192) -> only column max g (atomic, no store)
  k_gemm<<<dim3(32,8,4),256,0,stream>>>(Wf6, 192, Xcat, bf6, nullptr, genc, 1024, 192, 1);
  // bias7[b][o] = W7[:, :1024] @ g + bf7
  k_gemv7<<<dim3(128,4),256,0,stream>>>(Wf7, bf7, genc, bias7);
  // conv7: W7[:, 1024:1216] @ Xcat + bias7 (per batch)
  k_gemm<<<dim3(32,4,4),256,0,stream>>>(Wf7+1024, 1216, Xcat, bias7, h7, nullptr, 512, 192, 1|2|4);
  // conv8: 256x512
  k_gemm<<<dim3(32,2,4),256,0,stream>>>(Wf8, 512, h7, bf8, h8, nullptr, 256, 512, 1|2);
  // conv9: 13x256, no bias/relu -> d_out
  k_gemm<<<dim3(32,1,4),256,0,stream>>>(W9, 256, h8, nullptr, (float*)d_out, nullptr, 13, 256, 2);
}

// Round 2
// 1261.745 us; speedup vs baseline: 2.4354x; 2.4354x over previous
//
#include <hip/hip_runtime.h>
#include <math.h>

#define N_PTS 4096
#define BATCH 4
#define KNB 20

__device__ __forceinline__ float lrelu(float v){ return fmaxf(v, 0.2f*v); }
__device__ __forceinline__ unsigned fenc(float f){ unsigned u=__float_as_uint(f); return (u&0x80000000u)?~u:(u|0x80000000u); }
__device__ __forceinline__ float fdec(unsigned k){ return (k&0x80000000u)?__uint_as_float(k&0x7fffffffu):__uint_as_float(~k); }

// ---- prep: fold BN scale into weights ----
__global__ void k_scale_rows(const float* __restrict__ W, const float* __restrict__ bn,
                             float* __restrict__ Wf, float* __restrict__ bias, int O, int C){
  int i = blockIdx.x*256 + threadIdx.x;
  if (i >= O*C) return;
  int o = i / C;
  float s = bn[o] / sqrtf(bn[3*O+o] + 1e-5f);
  Wf[i] = W[i]*s;
  if (i % C == 0) bias[o] = bn[O+o] - s*bn[2*O+o];
}

// transposed float4-chunk layout: dst[(c/4)*256 + o*4 + c%4], O=64 fixed
__global__ void k_build_T4(const float* __restrict__ W, int ldw, const float* __restrict__ bn,
                           float* __restrict__ dst, float* __restrict__ bias,
                           int c0, int diffoff, int Csrc){
  int o = threadIdx.x, c = blockIdx.x;
  float s = bn[o] / sqrtf(bn[192+o] + 1e-5f);
  float val = 0.f;
  if (c < Csrc){
    val = W[o*ldw + c0 + c];
    if (diffoff) val = W[o*ldw + c0 + diffoff + c] - val;
    val *= s;
  }
  dst[(c>>2)*256 + o*4 + (c&3)] = val;
  if (bias != nullptr && c==0) bias[o] = bn[64+o] - s*bn[128+o];
}

// U1[b][k][o] = sum_{c<6} s_o*W1[o][c]*x[b][c][k]  (first-KNN neighbors are points 0..19)
__global__ void k_build_U1(const float* __restrict__ x, const float* __restrict__ W1,
                           const float* __restrict__ bn, float* __restrict__ U1){
  int o = threadIdx.x, k = blockIdx.x, b = blockIdx.y;
  float s = bn[o] / sqrtf(bn[192+o] + 1e-5f);
  float acc = 0.f;
  #pragma unroll
  for (int c=0;c<6;c++) acc += W1[o*12+c] * x[(b*6+c)*N_PTS + k];
  U1[(b*KNB+k)*64 + o] = acc*s;
}

__global__ void k_init_g(unsigned* g){ g[blockIdx.x*256+threadIdx.x] = fenc(-INFINITY); }

// ---- edge block 1 (trivial neighbors 0..19) : conv1 + conv2 + maxpool ----
__global__ __launch_bounds__(256) void k_edge1(const float* __restrict__ x, const float* __restrict__ U1,
                        const float* __restrict__ W1dT4, const float* __restrict__ bf1,
                        const float* __restrict__ W2T4, const float* __restrict__ bf2,
                        float* __restrict__ x1t, float* __restrict__ Xcat, float* __restrict__ xx1){
  __shared__ float hb[4][KNB][64];
  int wid = threadIdx.x>>6, lane = threadIdx.x&63;
  int pt = blockIdx.x*4 + wid, b = pt>>12, n = pt&4095;
  float xv[8];
  #pragma unroll
  for (int c=0;c<6;c++) xv[c] = x[(b*6+c)*N_PTS + n];
  xv[6]=0.f; xv[7]=0.f;
  float w = bf1[lane];
  #pragma unroll
  for (int cb=0;cb<2;cb++){
    float4 wv = ((const float4*)W1dT4)[cb*64+lane];
    w = fmaf(wv.x, xv[cb*4+0], w); w = fmaf(wv.y, xv[cb*4+1], w);
    w = fmaf(wv.z, xv[cb*4+2], w); w = fmaf(wv.w, xv[cb*4+3], w);
  }
  const float* Ub = U1 + b*KNB*64;
  #pragma unroll
  for (int k=0;k<KNB;k++) hb[wid][k][lane] = lrelu(Ub[k*64+lane] + w);
  __syncthreads();
  float acc[KNB];
  #pragma unroll
  for (int k=0;k<KNB;k++) acc[k] = bf2[lane];
  for (int cb=0;cb<16;cb++){
    float4 wv = ((const float4*)W2T4)[cb*64+lane];
    #pragma unroll
    for (int k=0;k<KNB;k++){
      float4 a = *(const float4*)&hb[wid][k][cb*4];
      acc[k]=fmaf(wv.x,a.x,acc[k]); acc[k]=fmaf(wv.y,a.y,acc[k]);
      acc[k]=fmaf(wv.z,a.z,acc[k]); acc[k]=fmaf(wv.w,a.w,acc[k]);
    }
  }
  float mx = -INFINITY;
  #pragma unroll
  for (int k=0;k<KNB;k++) mx = fmaxf(mx, lrelu(acc[k]));
  x1t[(size_t)pt*64 + lane] = mx;
  Xcat[((size_t)b*192 + 0 + lane)*N_PTS + n] = mx;
  float sq = mx*mx;
  #pragma unroll
  for (int off=32; off; off>>=1) sq += __shfl_xor(sq, off);
  if (lane==0) xx1[pt] = sq;
}

// ---- KNN pairwise kernel: pd[b][i][j] = fma(2,dot,-xx_n) - xx_m, 128x128 tile, K=64 ----
__global__ __launch_bounds__(256) void k_knn_gemm(const float* __restrict__ xt, const float* __restrict__ xx,
                          float* __restrict__ pd, int q0, int S){
  __shared__ float As[64][132];
  __shared__ float Bs[64][132];
  int tid = threadIdx.x;
  int bx = blockIdx.x, by = blockIdx.y, b = blockIdx.z;
  const float* xb = xt + (size_t)b*N_PTS*64;
  #pragma unroll
  for (int p=0;p<8;p++){
    int row = (tid>>4) + p*16, c4 = tid&15;
    float4 av = *(const float4*)&xb[(size_t)(q0 + by*128 + row)*64 + c4*4];
    As[c4*4+0][row]=av.x; As[c4*4+1][row]=av.y; As[c4*4+2][row]=av.z; As[c4*4+3][row]=av.w;
    float4 bv = *(const float4*)&xb[(size_t)(bx*128 + row)*64 + c4*4];
    Bs[c4*4+0][row]=bv.x; Bs[c4*4+1][row]=bv.y; Bs[c4*4+2][row]=bv.z; Bs[c4*4+3][row]=bv.w;
  }
  __syncthreads();
  int u = tid&15, v = tid>>4;
  float acc[8][8];
  #pragma unroll
  for (int i=0;i<8;i++)
    #pragma unroll
    for (int j=0;j<8;j++) acc[i][j]=0.f;
  #pragma unroll 4
  for (int k=0;k<64;k++){
    float4 a0 = *(const float4*)&As[k][u*4];
    float4 a1 = *(const float4*)&As[k][64+u*4];
    float4 b0 = *(const float4*)&Bs[k][v*4];
    float4 b1 = *(const float4*)&Bs[k][64+v*4];
    float a[8] = {a0.x,a0.y,a0.z,a0.w,a1.x,a1.y,a1.z,a1.w};
    float bb[8] = {b0.x,b0.y,b0.z,b0.w,b1.x,b1.y,b1.z,b1.w};
    #pragma unroll
    for (int i=0;i<8;i++)
      #pragma unroll
      for (int j=0;j<8;j++)
        acc[i][j] = fmaf(a[i], bb[j], acc[i][j]);
  }
  float xn[8], xm[8];
  #pragma unroll
  for (int i=0;i<8;i++){
    int ri = (i<4)? u*4+i : 64+u*4+(i-4);
    xn[i] = xx[b*N_PTS + q0 + by*128 + ri];
  }
  #pragma unroll
  for (int j=0;j<8;j++){
    int cj = (j<4)? v*4+j : 64+v*4+(j-4);
    xm[j] = xx[b*N_PTS + bx*128 + cj];
  }
  #pragma unroll
  for (int i=0;i<8;i++){
    int ri = (i<4)? u*4+i : 64+u*4+(i-4);
    float* dst = pd + ((size_t)(b*S + q0*0 + by*128 + ri))*N_PTS + bx*128;
    float4 s0, s1;
    s0.x = fmaf(2.f,acc[i][0],-xn[i]) - xm[0];
    s0.y = fmaf(2.f,acc[i][1],-xn[i]) - xm[1];
    s0.z = fmaf(2.f,acc[i][2],-xn[i]) - xm[2];
    s0.w = fmaf(2.f,acc[i][3],-xn[i]) - xm[3];
    s1.x = fmaf(2.f,acc[i][4],-xn[i]) - xm[4];
    s1.y = fmaf(2.f,acc[i][5],-xn[i]) - xm[5];
    s1.z = fmaf(2.f,acc[i][6],-xn[i]) - xm[6];
    s1.w = fmaf(2.f,acc[i][7],-xn[i]) - xm[7];
    *(float4*)&dst[v*4] = s0;
    *(float4*)&dst[64+v*4] = s1;
  }
}

// ---- top-20, exact lax.top_k tie-break (val desc, index asc); one wave per query ----
// Grouped local-best tournament: 4 cached group bests per lane; per round only the
// owning lane rescans its group of 16. Keys: (fenc(v) desc, LO asc-index) with
// LO = 4095 - m so larger LO = smaller index; keys globally unique.
__global__ __launch_bounds__(256) void k_topk20(const float* __restrict__ pdbuf, int* __restrict__ idxout,
                                                int q0, int sshift){
  int wid = threadIdx.x>>6, lane = threadIdx.x&63;
  int gw = blockIdx.x*4 + wid;
  int S = 1 << sshift;
  int b = gw >> sshift, i = gw & (S-1);
  const float* row = pdbuf + ((size_t)b*S + i)*N_PTS;
  int lane4 = lane*4;
  int lobase = 4095 - lane4;
  // load 64 values (16x float4); m(t) = (t>>2)*256 + lane*4 + (t&3); encode once
  unsigned ve[64];
  #pragma unroll
  for (int t4=0;t4<16;t4++){
    float4 f = *(const float4*)&row[t4*256 + lane4];
    unsigned u;
    u=__float_as_uint(f.x); ve[t4*4+0] = u ^ ((unsigned)((int)u>>31) | 0x80000000u);
    u=__float_as_uint(f.y); ve[t4*4+1] = u ^ ((unsigned)((int)u>>31) | 0x80000000u);
    u=__float_as_uint(f.z); ve[t4*4+2] = u ^ ((unsigned)((int)u>>31) | 0x80000000u);
    u=__float_as_uint(f.w); ve[t4*4+3] = u ^ ((unsigned)((int)u>>31) | 0x80000000u);
  }
  // init 4 group bests (groups of 16 consecutive t), independent chains
  unsigned gh[4]; int gl[4];
  #pragma unroll
  for (int g=0; g<4; g++){ gh[g]=0u; gl[g]=-1; }
  #pragma unroll
  for (int s=0; s<16; s++){
    #pragma unroll
    for (int g=0; g<4; g++){
      int t = g*16 + s;
      int LO = lobase - ((t>>2)*256 + (t&3));
      bool bt = (ve[t] > gh[g]) || (ve[t]==gh[g] && LO > gl[g]);
      if (bt){ gh[g]=ve[t]; gl[g]=LO; }
    }
  }
  int myidx = 0;
  for (int r=0; r<KNB; r++){
    // combine 4 group bests
    unsigned ch = gh[0]; int cl = gl[0];
    if (gh[1]>ch || (gh[1]==ch && gl[1]>cl)){ ch=gh[1]; cl=gl[1]; }
    if (gh[2]>ch || (gh[2]==ch && gl[2]>cl)){ ch=gh[2]; cl=gl[2]; }
    if (gh[3]>ch || (gh[3]==ch && gl[3]>cl)){ ch=gh[3]; cl=gl[3]; }
    // wave reduce
    unsigned wh = ch; int wl = cl;
    #pragma unroll
    for (int off=32; off; off>>=1){
      unsigned oh = (unsigned)__shfl_xor((int)wh, off);
      int      ol = __shfl_xor(wl, off);
      if (oh>wh || (oh==wh && ol>wl)){ wh=oh; wl=ol; }
    }
    if (lane==r) myidx = 4095 - wl;
    // owner rescan of the winning group only (exec-masked for all other lanes)
    #pragma unroll
    for (int g=0; g<4; g++){
      if (gh[g]==wh && gl[g]==wl){
        unsigned nh = 0u; int nl = -1;
        #pragma unroll
        for (int s=0; s<16; s++){
          int t = g*16 + s;
          int LO = lobase - ((t>>2)*256 + (t&3));
          bool taken = (ve[t]>wh) || (ve[t]==wh && LO>=wl);
          bool bt = (!taken) && ((ve[t]>nh) || (ve[t]==nh && LO>nl));
          if (bt){ nh=ve[t]; nl=LO; }
        }
        gh[g]=nh; gl[g]=nl;
      }
    }
  }
  if (lane < KNB) idxout[((size_t)b*N_PTS + (q0+i))*KNB + lane] = myidx;
}

// ---- edge conv block (gather + 1 or 2 convs + maxpool) ----
template<int TWO>
__global__ __launch_bounds__(256) void k_edgeconv(const float* __restrict__ xt, const int* __restrict__ idx,
    const float* __restrict__ WLT4, const float* __restrict__ WRT4, const float* __restrict__ bfa,
    const float* __restrict__ W2T4, const float* __restrict__ bfb,
    float* __restrict__ xout, float* __restrict__ Xcat, int rowofs, float* __restrict__ xxout){
  __shared__ float A[4][KNB][64];
  __shared__ float H[4][TWO?KNB:1][64];
  __shared__ float Cs[4][64];
  int wid = threadIdx.x>>6, lane = threadIdx.x&63;
  int pt = blockIdx.x*4 + wid, b = pt>>12, n = pt&4095;
  const float* xb = xt + (size_t)b*N_PTS*64;
  float ctr = xb[(size_t)n*64 + lane];
  Cs[wid][lane] = ctr;
  const int* ip = idx + (size_t)pt*KNB;
  #pragma unroll
  for (int k=0;k<KNB;k++){
    int m = ip[k];
    A[wid][k][lane] = xb[(size_t)m*64 + lane] - ctr;
  }
  __syncthreads();
  float e = bfa[lane];
  #pragma unroll
  for (int cb=0;cb<16;cb++){
    float4 wv = ((const float4*)WRT4)[cb*64+lane];
    float4 cv = *(const float4*)&Cs[wid][cb*4];
    e=fmaf(wv.x,cv.x,e); e=fmaf(wv.y,cv.y,e); e=fmaf(wv.z,cv.z,e); e=fmaf(wv.w,cv.w,e);
  }
  float acc[KNB];
  #pragma unroll
  for (int k=0;k<KNB;k++) acc[k]=e;
  for (int cb=0;cb<16;cb++){
    float4 wv = ((const float4*)WLT4)[cb*64+lane];
    #pragma unroll
    for (int k=0;k<KNB;k++){
      float4 a = *(const float4*)&A[wid][k][cb*4];
      acc[k]=fmaf(wv.x,a.x,acc[k]); acc[k]=fmaf(wv.y,a.y,acc[k]);
      acc[k]=fmaf(wv.z,a.z,acc[k]); acc[k]=fmaf(wv.w,a.w,acc[k]);
    }
  }
  if (TWO){
    #pragma unroll
    for (int k=0;k<KNB;k++) H[wid][k][lane] = lrelu(acc[k]);
    __syncthreads();
    #pragma unroll
    for (int k=0;k<KNB;k++) acc[k] = bfb[lane];
    for (int cb=0;cb<16;cb++){
      float4 wv = ((const float4*)W2T4)[cb*64+lane];
      #pragma unroll
      for (int k=0;k<KNB;k++){
        float4 a = *(const float4*)&H[wid][k][cb*4];
        acc[k]=fmaf(wv.x,a.x,acc[k]); acc[k]=fmaf(wv.y,a.y,acc[k]);
        acc[k]=fmaf(wv.z,a.z,acc[k]); acc[k]=fmaf(wv.w,a.w,acc[k]);
      }
    }
  }
  float mx = -INFINITY;
  #pragma unroll
  for (int k=0;k<KNB;k++) mx = fmaxf(mx, lrelu(acc[k]));
  if (xout) xout[(size_t)pt*64 + lane] = mx;
  Xcat[((size_t)b*192 + rowofs + lane)*N_PTS + n] = mx;
  if (xxout){
    float sq = mx*mx;
    #pragma unroll
    for (int off=32;off;off>>=1) sq += __shfl_xor(sq,off);
    if (lane==0) xxout[pt] = sq;
  }
}

// ---- generic fp32 GEMM: C[b][o][n] = act(A(OxK) @ B[b](KxN) + bias), optional col-max atomic ----
// flags: 1=leakyrelu, 2=store C, 4=bias per batch
__global__ __launch_bounds__(256) void k_gemm(const float* __restrict__ A, int lda,
        const float* __restrict__ B, const float* __restrict__ bias,
        float* __restrict__ C, unsigned* __restrict__ gmax,
        int O, int K, int flags){
  __shared__ float As[64][132];
  __shared__ float Bs[64][132];
  int tid = threadIdx.x, bx = blockIdx.x, by = blockIdx.y, b = blockIdx.z;
  int u = tid&15, v = tid>>4;
  float acc[8][8];
  #pragma unroll
  for (int i=0;i<8;i++)
    #pragma unroll
    for (int j=0;j<8;j++) acc[i][j]=0.f;
  const float* Bb = B + (size_t)b*K*N_PTS;
  for (int kt=0; kt<K; kt+=64){
    #pragma unroll
    for (int p=0;p<8;p++){
      int row = (tid>>4) + p*16, c4 = tid&15;
      int ga = by*128 + row;
      float4 av = (ga < O) ? *(const float4*)&A[(size_t)ga*lda + kt + c4*4] : make_float4(0.f,0.f,0.f,0.f);
      As[c4*4+0][row]=av.x; As[c4*4+1][row]=av.y; As[c4*4+2][row]=av.z; As[c4*4+3][row]=av.w;
      int kk = p*8 + (tid>>5), n4 = tid&31;
      float4 bv = *(const float4*)&Bb[(size_t)(kt+kk)*N_PTS + bx*128 + n4*4];
      *(float4*)&Bs[kk][n4*4] = bv;
    }
    __syncthreads();
    #pragma unroll 4
    for (int k=0;k<64;k++){
      float4 a0 = *(const float4*)&As[k][u*4];
      float4 a1 = *(const float4*)&As[k][64+u*4];
      float4 b0 = *(const float4*)&Bs[k][v*4];
      float4 b1 = *(const float4*)&Bs[k][64+v*4];
      float a[8] = {a0.x,a0.y,a0.z,a0.w,a1.x,a1.y,a1.z,a1.w};
      float bb[8] = {b0.x,b0.y,b0.z,b0.w,b1.x,b1.y,b1.z,b1.w};
      #pragma unroll
      for (int i=0;i<8;i++)
        #pragma unroll
        for (int j=0;j<8;j++)
          acc[i][j] = fmaf(a[i], bb[j], acc[i][j]);
    }
    __syncthreads();
  }
  bool relu = flags&1, store = flags&2, pbb = flags&4;
  float rowm[8];
  #pragma unroll
  for (int i=0;i<8;i++){
    int rl = (i<4)? u*4+i : 64+u*4+(i-4);
    int ri = by*128 + rl;
    float bvv = (bias != nullptr && ri < O) ? (pbb ? bias[b*O+ri] : bias[ri]) : 0.f;
    float vals[8];
    #pragma unroll
    for (int j=0;j<8;j++){
      float y = acc[i][j] + bvv;
      if (relu) y = lrelu(y);
      vals[j]=y;
    }
    if (store && ri < O){
      float* dst = C + ((size_t)b*O+ri)*N_PTS + bx*128;
      *(float4*)&dst[v*4] = make_float4(vals[0],vals[1],vals[2],vals[3]);
      *(float4*)&dst[64+v*4] = make_float4(vals[4],vals[5],vals[6],vals[7]);
    }
    float m = vals[0];
    #pragma unroll
    for (int j=1;j<8;j++) m = fmaxf(m, vals[j]);
    rowm[i] = m;
  }
  if (gmax != nullptr){
    float* red = &Bs[0][0];   // reuse as [128][16]
    #pragma unroll
    for (int i=0;i<8;i++){
      int rl = (i<4)? u*4+i : 64+u*4+(i-4);
      red[rl*16 + v] = rowm[i];
    }
    __syncthreads();
    if (tid < 128){
      float m = red[tid*16];
      #pragma unroll
      for (int j=1;j<16;j++) m = fmaxf(m, red[tid*16+j]);
      atomicMax(&gmax[b*1024 + by*128 + tid], fenc(m));
    }
  }
}

// bias7[b][o] = sum_{c<1024} Wf7[o][c]*g[b][c] + bf7[o]
__global__ __launch_bounds__(256) void k_gemv7(const float* __restrict__ Wf7, const float* __restrict__ bf7,
                        const unsigned* __restrict__ g, float* __restrict__ bias7){
  int wid = threadIdx.x>>6, lane = threadIdx.x&63;
  int o = blockIdx.x*4 + wid, b = blockIdx.y;
  const float* wr = Wf7 + (size_t)o*1216;
  const unsigned* gb = g + b*1024;
  float acc = 0.f;
  for (int c = lane; c < 1024; c += 64)
    acc = fmaf(wr[c], fdec(gb[c]), acc);
  #pragma unroll
  for (int off=32; off; off>>=1) acc += __shfl_xor(acc, off);
  if (lane==0) bias7[b*512+o] = acc + bf7[o];
}

extern "C" void kernel_launch(void* const* d_in, const int* in_sizes, int n_in,
                              void* d_out, int out_size, void* d_ws, size_t ws_size,
                              hipStream_t stream){
  const float* x  = (const float*)d_in[0];
  const float* W1 = (const float*)d_in[1];
  const float* W2 = (const float*)d_in[2];
  const float* W3 = (const float*)d_in[3];
  const float* W4 = (const float*)d_in[4];
  const float* W5 = (const float*)d_in[5];
  const float* W6 = (const float*)d_in[6];
  const float* W7 = (const float*)d_in[7];
  const float* W8 = (const float*)d_in[8];
  const float* W9 = (const float*)d_in[9];
  const float* bn1 = (const float*)d_in[10];
  const float* bn2 = (const float*)d_in[11];
  const float* bn3 = (const float*)d_in[12];
  const float* bn4 = (const float*)d_in[13];
  const float* bn5 = (const float*)d_in[14];
  const float* bn6 = (const float*)d_in[15];
  const float* bn7 = (const float*)d_in[16];
  const float* bn8 = (const float*)d_in[17];

  float* ws = (float*)d_ws;
  size_t off = 0;
  auto alloc = [&](size_t nf){ float* p = ws + off; off += (nf + 63) & ~(size_t)63; return p; };
  float* Wf6 = alloc(1024*192);   float* bf6 = alloc(1024);
  float* Wf7 = alloc((size_t)512*1216); float* bf7 = alloc(512);
  float* Wf8 = alloc(256*512);    float* bf8 = alloc(256);
  float* W1dT4 = alloc(8*64);     float* bf1 = alloc(64);
  float* W2T4  = alloc(64*64);    float* bf2 = alloc(64);
  float* W3LT4 = alloc(64*64);    float* W3RT4 = alloc(64*64); float* bf3 = alloc(64);
  float* W4T4  = alloc(64*64);    float* bf4 = alloc(64);
  float* W5LT4 = alloc(64*64);    float* W5RT4 = alloc(64*64); float* bf5 = alloc(64);
  float* U1  = alloc(4*KNB*64);
  float* x1t = alloc((size_t)4*N_PTS*64);
  float* x2t = alloc((size_t)4*N_PTS*64);
  float* Xcat = alloc((size_t)4*192*N_PTS);
  float* xx1 = alloc(4*N_PTS);
  float* xx2 = alloc(4*N_PTS);
  int* idx1 = (int*)alloc((size_t)4*N_PTS*KNB);
  int* idx2 = (int*)alloc((size_t)4*N_PTS*KNB);
  unsigned* genc = (unsigned*)alloc(4*1024);
  float* bias7 = alloc(4*512);
  float* h8 = alloc((size_t)4*256*N_PTS);
  // pdbuf takes the remainder; pick largest power-of-two stripe S (<=4096, >=512) that fits
  size_t remaining = (ws_size / 4 > off) ? (ws_size / 4 - off) : 0;
  int S = 4096;
  while (S > 512 && (size_t)4*S*N_PTS + 1024 > remaining) S >>= 1;
  int sshift = 31 - __builtin_clz(S);
  float* pdbuf = alloc((size_t)4*S*N_PTS);   // also reused as h7 (needs 32 MB <= pdbuf)
  float* h7 = pdbuf;

  // prep (every call: deterministic)
  k_scale_rows<<<(1024*192+255)/256,256,0,stream>>>(W6, bn6, Wf6, bf6, 1024, 192);
  k_scale_rows<<<(512*1216+255)/256,256,0,stream>>>(W7, bn7, Wf7, bf7, 512, 1216);
  k_scale_rows<<<(256*512+255)/256,256,0,stream>>>(W8, bn8, Wf8, bf8, 256, 512);
  k_build_T4<<<8,64,0,stream>>>(W1, 12, bn1, W1dT4, bf1, 0, 6, 6);     // (W1R - W1L), pad to 8
  k_build_T4<<<64,64,0,stream>>>(W2, 64, bn2, W2T4, bf2, 0, 0, 64);
  k_build_T4<<<64,64,0,stream>>>(W3, 128, bn3, W3LT4, bf3, 0, 0, 64);
  k_build_T4<<<64,64,0,stream>>>(W3, 128, bn3, W3RT4, nullptr, 64, 0, 64);
  k_build_T4<<<64,64,0,stream>>>(W4, 64, bn4, W4T4, bf4, 0, 0, 64);
  k_build_T4<<<64,64,0,stream>>>(W5, 128, bn5, W5LT4, bf5, 0, 0, 64);
  k_build_T4<<<64,64,0,stream>>>(W5, 128, bn5, W5RT4, nullptr, 64, 0, 64);
  k_build_U1<<<dim3(KNB,4),64,0,stream>>>(x, W1, bn1, U1);
  k_init_g<<<16,256,0,stream>>>(genc);

  // edge block 1 (neighbors = points 0..19 since KNN input is empty slice)
  k_edge1<<<4096,256,0,stream>>>(x, U1, W1dT4, bf1, W2T4, bf2, x1t, Xcat, xx1);

  int nstripe = N_PTS / S;
  // KNN on x1
  for (int s=0;s<nstripe;s++){
    k_knn_gemm<<<dim3(32,S/128,4),256,0,stream>>>(x1t, xx1, pdbuf, s*S, S);
    k_topk20<<<S,256,0,stream>>>(pdbuf, idx1, s*S, sshift);
  }

  // edge block 2 (two convs)
  k_edgeconv<1><<<4096,256,0,stream>>>(x1t, idx1, W3LT4, W3RT4, bf3, W4T4, bf4, x2t, Xcat, 64, xx2);

  // KNN on x2
  for (int s=0;s<nstripe;s++){
    k_knn_gemm<<<dim3(32,S/128,4),256,0,stream>>>(x2t, xx2, pdbuf, s*S, S);
    k_topk20<<<S,256,0,stream>>>(pdbuf, idx2, s*S, sshift);
  }

  // edge block 3 (one conv)
  k_edgeconv<0><<<4096,256,0,stream>>>(x2t, idx2, W5LT4, W5RT4, bf5, nullptr, nullptr, nullptr, Xcat, 128, nullptr);

  // conv6 (1024x192) -> only column max g (atomic, no store)
  k_gemm<<<dim3(32,8,4),256,0,stream>>>(Wf6, 192, Xcat, bf6, nullptr, genc, 1024, 192, 1);
  // bias7[b][o] = W7[:, :1024] @ g + bf7
  k_gemv7<<<dim3(128,4),256,0,stream>>>(Wf7, bf7, genc, bias7);
  // conv7: W7[:, 1024:1216] @ Xcat + bias7 (per batch)
  k_gemm<<<dim3(32,4,4),256,0,stream>>>(Wf7+1024, 1216, Xcat, bias7, h7, nullptr, 512, 192, 1|2|4);
  // conv8: 256x512
  k_gemm<<<dim3(32,2,4),256,0,stream>>>(Wf8, 512, h7, bf8, h8, nullptr, 256, 512, 1|2);
  // conv9: 13x256, no bias/relu -> d_out
  k_gemm<<<dim3(32,1,4),256,0,stream>>>(W9, 256, h8, nullptr, (float*)d_out, nullptr, 13, 256, 2);
}